// Round 6
// baseline (213.300 us; speedup 1.0000x reference)
//
#include <hip/hip_runtime.h>
#include <hip/hip_fp16.h>

#define DD 4096
#define NROWS 16384
#define EPS 1e-6f

// clang vector types — valid operands for __builtin_nontemporal_load/store
typedef float  fx4 __attribute__((ext_vector_type(4)));
typedef int    ix4 __attribute__((ext_vector_type(4)));

// ws layout:
//   +0        : float gmax
//   +256      : float rowmax[16384]
//   +256+64K  : float rstd[16384]
//   +1MB      : fp16 yg[64M] = (x+res)*gamma, UNNORMALIZED (128 MB)

struct H4 { __half2 a, b; };  // 4 halfs, 8 bytes

// Pass 1: ONE WAVE PER ROW. No __syncthreads, no LDS. Each wave streams its
// row (16 float4/lane), stores fp16((x+res)*gamma) immediately, reduces
// ss/mx with wave shuffles only. Tail cost amortized over 160 KB/wave.
__global__ __launch_bounds__(256) void pass1(
    const float* __restrict__ x, const float* __restrict__ res,
    const float* __restrict__ gamma, H4* __restrict__ yg,
    float* __restrict__ rstd, float* __restrict__ rowmax) {
  const int wave = threadIdx.x >> 6;
  const int lane = threadIdx.x & 63;
  const int row = blockIdx.x * 4 + wave;

  const fx4* x4 = (const fx4*)(x + (size_t)row * DD);
  const fx4* r4 = (const fx4*)(res + (size_t)row * DD);
  const fx4* g4 = (const fx4*)gamma;
  H4* yrow = yg + (size_t)row * (DD / 4);

  float ss = 0.f, mx = 0.f;
#pragma unroll 4
  for (int i = 0; i < 16; ++i) {
    const int idx = i * 64 + lane;  // coalesced 1KB/wave-instr
    fx4 xv = __builtin_nontemporal_load(&x4[idx]);   // read-once: keep L3
    fx4 rv = __builtin_nontemporal_load(&r4[idx]);   //   for yg instead
    fx4 gv = g4[idx];                                // gamma: cached
    float y0 = xv.x + rv.x, y1 = xv.y + rv.y;
    float y2 = xv.z + rv.z, y3 = xv.w + rv.w;
    ss += y0 * y0 + y1 * y1 + y2 * y2 + y3 * y3;
    float p0 = y0 * gv.x, p1 = y1 * gv.y, p2 = y2 * gv.z, p3 = y3 * gv.w;
    mx = fmaxf(mx, fmaxf(fmaxf(fabsf(p0), fabsf(p1)),
                         fmaxf(fabsf(p2), fabsf(p3))));
    H4 h;
    h.a = __floats2half2_rn(p0, p1);
    h.b = __floats2half2_rn(p2, p3);
    yrow[idx] = h;  // normal store: want yg L3-resident for pass2
  }

  // wave64 butterfly — no cross-wave communication needed
#pragma unroll
  for (int off = 32; off > 0; off >>= 1) {
    ss += __shfl_down(ss, off, 64);
    mx = fmaxf(mx, __shfl_down(mx, off, 64));
  }
  if (lane == 0) {
    float rs = rsqrtf(ss * (1.0f / DD) + EPS);
    rstd[row] = rs;
    rowmax[row] = mx * rs;  // |normalized output| row max
  }
}

__global__ __launch_bounds__(1024) void reduce_gmax(
    const float* __restrict__ rowmax, float* __restrict__ gmax) {
  const int t = threadIdx.x;
  float m = 0.f;
#pragma unroll
  for (int i = 0; i < NROWS / 1024; ++i) m = fmaxf(m, rowmax[t + i * 1024]);
#pragma unroll
  for (int off = 32; off > 0; off >>= 1) m = fmaxf(m, __shfl_down(m, off, 64));
  __shared__ float s[16];
  if ((t & 63) == 0) s[t >> 6] = m;
  __syncthreads();
  if (t == 0) {
    float r = s[0];
#pragma unroll
    for (int i = 1; i < 16; ++i) r = fmaxf(r, s[i]);
    *gmax = r;
  }
}

// Pass 2: q = clamp(rn(fp16(y*gamma) * rstd[row] * 127/gmax)). Each block
// covers 2048 contiguous elements = half a row -> uniform rstd index.
__global__ __launch_bounds__(256) void pass2(
    const __half* __restrict__ yg, const float* __restrict__ rstd,
    const float* __restrict__ gmax, int* __restrict__ out) {
  const int row = blockIdx.x >> 1;
  const float c = rstd[row] * (127.0f / *gmax);
  const size_t base = ((size_t)blockIdx.x * 256 + threadIdx.x) * 8;
  union { ix4 v; __half h[8]; } u;
  u.v = *(const ix4*)(yg + base);  // 16B coalesced fp16 load (L3-hot)
  ix4 q0, q1;
  q0.x = min(max(__float2int_rn(__half2float(u.h[0]) * c), -128), 127);
  q0.y = min(max(__float2int_rn(__half2float(u.h[1]) * c), -128), 127);
  q0.z = min(max(__float2int_rn(__half2float(u.h[2]) * c), -128), 127);
  q0.w = min(max(__float2int_rn(__half2float(u.h[3]) * c), -128), 127);
  q1.x = min(max(__float2int_rn(__half2float(u.h[4]) * c), -128), 127);
  q1.y = min(max(__float2int_rn(__half2float(u.h[5]) * c), -128), 127);
  q1.z = min(max(__float2int_rn(__half2float(u.h[6]) * c), -128), 127);
  q1.w = min(max(__float2int_rn(__half2float(u.h[7]) * c), -128), 127);
  // output never re-read: NT stores avoid evicting yg from L3
  __builtin_nontemporal_store(q0, (ix4*)(out + base));
  __builtin_nontemporal_store(q1, (ix4*)(out + base + 4));
}

// ---- Fallback (ws too small): recompute path, atomic-free ----
__global__ __launch_bounds__(256) void pass1_nb(
    const float* __restrict__ x, const float* __restrict__ res,
    const float* __restrict__ gamma, float* __restrict__ rstd,
    float* __restrict__ rowmax) {
  const int wave = threadIdx.x >> 6;
  const int lane = threadIdx.x & 63;
  const int row = blockIdx.x * 4 + wave;
  const fx4* x4 = (const fx4*)(x + (size_t)row * DD);
  const fx4* r4 = (const fx4*)(res + (size_t)row * DD);
  const fx4* g4 = (const fx4*)gamma;
  float ss = 0.f, mx = 0.f;
#pragma unroll 4
  for (int i = 0; i < 16; ++i) {
    const int idx = i * 64 + lane;
    fx4 xv = x4[idx], rv = r4[idx], gv = g4[idx];
    float y0 = xv.x + rv.x, y1 = xv.y + rv.y;
    float y2 = xv.z + rv.z, y3 = xv.w + rv.w;
    ss += y0 * y0 + y1 * y1 + y2 * y2 + y3 * y3;
    mx = fmaxf(mx, fmaxf(fmaxf(fabsf(y0 * gv.x), fabsf(y1 * gv.y)),
                         fmaxf(fabsf(y2 * gv.z), fabsf(y3 * gv.w))));
  }
#pragma unroll
  for (int off = 32; off > 0; off >>= 1) {
    ss += __shfl_down(ss, off, 64);
    mx = fmaxf(mx, __shfl_down(mx, off, 64));
  }
  if (lane == 0) {
    float rs = rsqrtf(ss * (1.0f / DD) + EPS);
    rstd[row] = rs;
    rowmax[row] = mx * rs;
  }
}

__global__ __launch_bounds__(256) void pass2_nb(
    const float* __restrict__ x, const float* __restrict__ res,
    const float* __restrict__ gamma, const float* __restrict__ rstd,
    const float* __restrict__ gmax, int* __restrict__ out) {
  const int row = blockIdx.x;
  const int t = threadIdx.x;
  const float c = rstd[row] * (127.0f / *gmax);
  const fx4* x4 = (const fx4*)(x + (size_t)row * DD);
  const fx4* r4 = (const fx4*)(res + (size_t)row * DD);
  const fx4* g4 = (const fx4*)gamma;
  ix4* o4 = (ix4*)(out + (size_t)row * DD);
#pragma unroll
  for (int i = 0; i < 4; ++i) {
    const int idx = t + i * 256;
    fx4 xv = x4[idx], rv = r4[idx], gv = g4[idx];
    ix4 q;
    q.x = min(max(__float2int_rn((xv.x + rv.x) * gv.x * c), -128), 127);
    q.y = min(max(__float2int_rn((xv.y + rv.y) * gv.y * c), -128), 127);
    q.z = min(max(__float2int_rn((xv.z + rv.z) * gv.z * c), -128), 127);
    q.w = min(max(__float2int_rn((xv.w + rv.w) * gv.w * c), -128), 127);
    o4[idx] = q;
  }
}

extern "C" void kernel_launch(void* const* d_in, const int* in_sizes, int n_in,
                              void* d_out, int out_size, void* d_ws, size_t ws_size,
                              hipStream_t stream) {
  const float* x     = (const float*)d_in[0];
  const float* res   = (const float*)d_in[1];
  const float* gamma = (const float*)d_in[2];
  int* out = (int*)d_out;

  float* gmax   = (float*)d_ws;
  float* rowmax = (float*)((char*)d_ws + 256);
  float* rstd   = (float*)((char*)d_ws + 256 + NROWS * 4);
  const size_t yg_off = (size_t)1 << 20;
  const size_t need = yg_off + (size_t)NROWS * DD * 2;  // ~129 MB

  if (ws_size >= need) {
    H4* yg = (H4*)((char*)d_ws + yg_off);
    pass1<<<NROWS / 4, 256, 0, stream>>>(x, res, gamma, yg, rstd, rowmax);
    reduce_gmax<<<1, 1024, 0, stream>>>(rowmax, gmax);
    pass2<<<((size_t)NROWS * DD) / 2048, 256, 0, stream>>>(
        (const __half*)yg, rstd, gmax, out);
  } else {
    pass1_nb<<<NROWS / 4, 256, 0, stream>>>(x, res, gamma, rstd, rowmax);
    reduce_gmax<<<1, 1024, 0, stream>>>(rowmax, gmax);
    pass2_nb<<<NROWS, 256, 0, stream>>>(x, res, gamma, rstd, gmax, out);
  }
}